// Round 1
// baseline (505.943 us; speedup 1.0000x reference)
//
#include <hip/hip_runtime.h>

// grica power-whitening encoder, MI355X.
//   Kp k_prep    : zero C0 accumulator + split Wfc f32 -> bf16 hi/lo
//   K1 k_pass1m  : MFMA split-bf16: y = x@Wfc^T (f32 to d_out) and C0sum += y^T y.
//                  x loads register-prefetched one ks ahead + across the tile
//                  boundary (issued under the C-pass MFMAs) to stay BW-bound.
//   K2 k_whiten_ns : W = C^(-1/2) via coupled Newton-Schulz (10 iters).
//   K3 k_yw      : d_out = d_out @ W in place (W symmetric).

#define LDS_STRIDE 68    // whiten kernel only
#define NS_ITERS 10
#define YT_STRIDE 136    // yT row stride in shorts (128 + 8 pad)

typedef __attribute__((ext_vector_type(8))) short bf16x8;
typedef __attribute__((ext_vector_type(4))) float f32x4;

// split Wfc (64x256 f32) into truncation-split bf16 hi/lo, same layout.
// also zeroes the 64x64 C0 accumulator (first 4096 lanes).
__global__ __launch_bounds__(256) void k_prep(const float* __restrict__ Wfc,
                                              unsigned short* __restrict__ Wh,
                                              unsigned short* __restrict__ Wl,
                                              float* __restrict__ C0sum){
  const int i = blockIdx.x*256 + threadIdx.x;    // grid 64 -> 16384
  if (i < 4096) C0sum[i] = 0.f;
  const float f = Wfc[i];
  const unsigned b  = __float_as_uint(f);
  const unsigned hb = b & 0xFFFF0000u;
  Wh[i] = (unsigned short)(hb >> 16);
  Wl[i] = (unsigned short)(__float_as_uint(f - __uint_as_float(hb)) >> 16);
}

__device__ __forceinline__ void split8(float4 u, float4 v, bf16x8 &hi, bf16x8 &lo){
  const float f[8] = {u.x,u.y,u.z,u.w, v.x,v.y,v.z,v.w};
  #pragma unroll
  for (int i=0;i<8;i++){
    const unsigned b  = __float_as_uint(f[i]);
    const unsigned hb = b & 0xFFFF0000u;
    hi[i] = (short)(hb >> 16);
    lo[i] = (short)(__float_as_uint(f[i] - __uint_as_float(hb)) >> 16);
  }
}

#define MFMA16(a,b,c) __builtin_amdgcn_mfma_f32_16x16x32_bf16((a),(b),(c),0,0,0)

__global__ __launch_bounds__(256,3) void k_pass1m(const float* __restrict__ x,
                                                  const unsigned short* __restrict__ Wh,
                                                  const unsigned short* __restrict__ Wl,
                                                  float* __restrict__ C0sum,
                                                  float* __restrict__ y,
                                                  int N, int ntiles){
  __shared__ __align__(16) unsigned short yT_hi[64*YT_STRIDE];
  __shared__ __align__(16) unsigned short yT_lo[64*YT_STRIDE];
  const int t  = threadIdx.x;
  const int wv = t>>6, l = t&63;
  const int lg = l>>4, lr = l&15;

  f32x4 accC[4];
  #pragma unroll
  for (int b=0;b<4;b++) accC[b] = (f32x4){0.f,0.f,0.f,0.f};

  // x-load prefetch registers: current ks data for both row-blocks
  float4 cA0[2], cA1[2];

  auto loadks = [&](long r0, int ks, float4* A0, float4* A1){
    const int kl = 32*ks + 8*lg;
    #pragma unroll
    for (int rb=0; rb<2; ++rb){
      const long row = r0 + 32*wv + 16*rb + lr;
      if (row < (long)N){
        A0[rb] = *(const float4*)&x[row*256 + kl];
        A1[rb] = *(const float4*)&x[row*256 + kl + 4];
      } else {
        A0[rb] = make_float4(0.f,0.f,0.f,0.f);
        A1[rb] = make_float4(0.f,0.f,0.f,0.f);
      }
    }
  };

  long r0 = (long)blockIdx.x*128;
  if (blockIdx.x < ntiles) loadks(r0, 0, cA0, cA1);

  for (int tile = blockIdx.x; tile < ntiles; tile += gridDim.x){

    // ---- y-GEMM: 128x64 tile, wave wv owns rows [32wv, 32wv+32)
    f32x4 accY[2][4];
    #pragma unroll
    for (int rb=0;rb<2;rb++)
      #pragma unroll
      for (int cb=0;cb<4;cb++) accY[rb][cb] = (f32x4){0.f,0.f,0.f,0.f};

    #pragma unroll 1
    for (int ks=0; ks<8; ++ks){
      // issue next-ks loads before consuming current (hide L2/HBM latency)
      float4 nA0[2], nA1[2];
      if (ks < 7) loadks(r0, ks+1, nA0, nA1);

      const int kl = 32*ks + 8*lg;
      bf16x8 ahi[2], alo[2];
      split8(cA0[0], cA1[0], ahi[0], alo[0]);
      split8(cA0[1], cA1[1], ahi[1], alo[1]);

      #pragma unroll
      for (int cb=0; cb<4; ++cb){
        const bf16x8 bhi = *(const bf16x8*)&Wh[(16*cb+lr)*256 + kl];
        const bf16x8 blo = *(const bf16x8*)&Wl[(16*cb+lr)*256 + kl];
        #pragma unroll
        for (int rb=0; rb<2; ++rb){
          accY[rb][cb] = MFMA16(ahi[rb], bhi, accY[rb][cb]);
          accY[rb][cb] = MFMA16(alo[rb], bhi, accY[rb][cb]);
          accY[rb][cb] = MFMA16(ahi[rb], blo, accY[rb][cb]);
        }
      }
      if (ks < 7){
        #pragma unroll
        for (int rb=0; rb<2; ++rb){ cA0[rb]=nA0[rb]; cA1[rb]=nA1[rb]; }
      }
    }

    // ---- epilogue: y -> global f32; yT -> LDS packed bf16 hi/lo
    // C/D layout (m89-verified): col = lane&15, row = 4*(lane>>4)+i
    #pragma unroll
    for (int rb=0; rb<2; ++rb){
      const int rloc = 32*wv + 16*rb + 4*lg;
      #pragma unroll
      for (int cb=0; cb<4; ++cb){
        const int c = 16*cb + lr;
        unsigned hh[4], ll[4];
        #pragma unroll
        for (int i=0;i<4;i++){
          const float f = accY[rb][cb][i];
          const long row = r0 + rloc + i;
          if (row < (long)N) y[row*64 + c] = f;
          const unsigned b  = __float_as_uint(f);
          const unsigned hb = b & 0xFFFF0000u;
          hh[i] = hb >> 16;
          ll[i] = __float_as_uint(f - __uint_as_float(hb)) >> 16;
        }
        *(uint2*)&yT_hi[c*YT_STRIDE + rloc] =
            make_uint2(hh[0] | (hh[1]<<16), hh[2] | (hh[3]<<16));
        *(uint2*)&yT_lo[c*YT_STRIDE + rloc] =
            make_uint2(ll[0] | (ll[1]<<16), ll[2] | (ll[3]<<16));
      }
    }
    __syncthreads();

    // ---- cross-tile prefetch: issue next tile's ks=0 x-loads here so the
    // HBM latency hides under the C-pass MFMAs below.
    const long nr0 = r0 + (long)gridDim.x*128;
    if (tile + gridDim.x < ntiles) loadks(nr0, 0, cA0, cA1);

    // ---- C-pass MFMA: C-tile row a=wv, b=0..3; A=y^T, B=y, both read from yT
    #pragma unroll 1
    for (int ksC=0; ksC<4; ++ksC){
      const int kc = 32*ksC + 8*lg;
      const bf16x8 cahi = *(const bf16x8*)&yT_hi[(16*wv+lr)*YT_STRIDE + kc];
      const bf16x8 calo = *(const bf16x8*)&yT_lo[(16*wv+lr)*YT_STRIDE + kc];
      #pragma unroll
      for (int b=0;b<4;b++){
        const bf16x8 cbhi = *(const bf16x8*)&yT_hi[(16*b+lr)*YT_STRIDE + kc];
        const bf16x8 cblo = *(const bf16x8*)&yT_lo[(16*b+lr)*YT_STRIDE + kc];
        accC[b] = MFMA16(cahi, cbhi, accC[b]);
        accC[b] = MFMA16(calo, cbhi, accC[b]);
        accC[b] = MFMA16(cahi, cblo, accC[b]);
      }
    }
    __syncthreads();   // yT consumed before next tile overwrites it

    r0 = nr0;
  }

  #pragma unroll
  for (int b=0;b<4;b++)
    #pragma unroll
    for (int i=0;i<4;i++){
      const int m = 16*wv + 4*lg + i;
      const int n = 16*b + lr;
      atomicAdd(&C0sum[m*64 + n], accC[b][i]);
    }
}

#define WMAXRED(s) { s=fmaxf(s,__shfl_xor(s,32)); s=fmaxf(s,__shfl_xor(s,16)); \
  s=fmaxf(s,__shfl_xor(s,8)); s=fmaxf(s,__shfl_xor(s,4)); \
  s=fmaxf(s,__shfl_xor(s,2)); s=fmaxf(s,__shfl_xor(s,1)); }

// Coupled Newton-Schulz for C^(-1/2): A=C/tau (Gershgorin tau), Y=A, Z=I;
// T = 1.5I-0.5ZY; Y<-YT; Z<-TZ;  Z -> A^(-1/2);  W = Z/sqrt(tau).
__global__ __launch_bounds__(256,1) void k_whiten_ns(const float* __restrict__ C0sum,
                                                     float* __restrict__ Wout,
                                                     float invN){
  __shared__ __align__(16) float B0[64*LDS_STRIDE];
  __shared__ __align__(16) float B1[64*LDS_STRIDE];
  __shared__ __align__(16) float B2[64*LDS_STRIDE];
  __shared__ __align__(16) float B3[64*LDS_STRIDE];
  __shared__ float sred[8];

  const int t = threadIdx.x;
  const int w = t>>6, l = t&63;
  const int di = t>>2, djb = (t&3)*16;
  const int rg = l&3, cg = l>>2;
  const int row0 = 16*w + 4*rg;

  float4 cv[4];
  float psum = 0.f;
  #pragma unroll
  for (int c=0;c<4;c++){
    cv[c] = *(const float4*)&C0sum[di*64 + djb + 4*c];
    psum += fabsf(cv[c].x)+fabsf(cv[c].y)+fabsf(cv[c].z)+fabsf(cv[c].w);
  }
  psum *= invN;
  psum += __shfl_xor(psum,1);
  psum += __shfl_xor(psum,2);
  float m = psum;
  WMAXRED(m);
  if (l==0) sred[w] = m;
  __syncthreads();
  const float tau = fmaxf(fmaxf(sred[0],sred[1]), fmaxf(sred[2],sred[3]));
  const float sA = invN/tau;

  #pragma unroll
  for (int c=0;c<4;c++){
    float4 v4 = cv[c];
    v4.x*=sA; v4.y*=sA; v4.z*=sA; v4.w*=sA;
    *(float4*)&B0[di*LDS_STRIDE + djb + 4*c] = v4;
    const int j0 = djb + 4*c;
    *(float4*)&B1[di*LDS_STRIDE + j0] = make_float4(
        (di==j0+0)?1.f:0.f, (di==j0+1)?1.f:0.f,
        (di==j0+2)?1.f:0.f, (di==j0+3)?1.f:0.f);
  }
  __syncthreads();

  float *pY=B0, *pZ=B1, *pT=B2, *pU=B3;

  auto mm = [&](float* __restrict__ D, const float* __restrict__ A,
                const float* __restrict__ Bm, bool isT){
    float acc[4][4];
    #pragma unroll
    for (int i=0;i<4;i++)
      #pragma unroll
      for (int j=0;j<4;j++) acc[i][j] = 0.f;
    #pragma unroll 1
    for (int c=0;c<4;c++){
      float arr[4][16];
      #pragma unroll
      for (int ri=0;ri<4;ri++)
        #pragma unroll
        for (int k4=0;k4<4;k4++){
          const float4 a4 = *(const float4*)&A[(row0+ri)*LDS_STRIDE + 16*c + 4*k4];
          arr[ri][4*k4+0]=a4.x; arr[ri][4*k4+1]=a4.y;
          arr[ri][4*k4+2]=a4.z; arr[ri][4*k4+3]=a4.w;
        }
      #pragma unroll
      for (int kk=0;kk<16;kk++){
        const float4 b = *(const float4*)&Bm[(16*c+kk)*LDS_STRIDE + 4*cg];
        #pragma unroll
        for (int ri=0;ri<4;ri++){
          acc[ri][0] += arr[ri][kk]*b.x;
          acc[ri][1] += arr[ri][kk]*b.y;
          acc[ri][2] += arr[ri][kk]*b.z;
          acc[ri][3] += arr[ri][kk]*b.w;
        }
      }
    }
    if (isT){
      #pragma unroll
      for (int ri=0;ri<4;ri++)
        #pragma unroll
        for (int j=0;j<4;j++)
          acc[ri][j] = -0.5f*acc[ri][j] + ((row0+ri == 4*cg+j) ? 1.5f : 0.f);
    }
    #pragma unroll
    for (int ri=0;ri<4;ri++)
      *(float4*)&D[(row0+ri)*LDS_STRIDE + 4*cg] =
          make_float4(acc[ri][0],acc[ri][1],acc[ri][2],acc[ri][3]);
    __syncthreads();
  };

  #pragma unroll 1
  for (int it=0; it<NS_ITERS; ++it){
    mm(pT, pZ, pY, true);
    if (it < NS_ITERS-1) mm(pU, pY, pT, false);
    mm(pY, pT, pZ, false);
    float* oY=pY; float* oZ=pZ; float* oU=pU;
    pY = oU; pZ = oY; pU = oZ;
  }

  const float fs = rsqrtf(tau);
  #pragma unroll
  for (int c=0;c<4;c++){
    float4 z4 = *(const float4*)&pZ[di*LDS_STRIDE + djb + 4*c];
    z4.x*=fs; z4.y*=fs; z4.z*=fs; z4.w*=fs;
    *(float4*)&Wout[di*64 + djb + 4*c] = z4;
  }
}

// In-place: yio[r][:] <- yio[r][:] @ W  (W symmetric 64x64 in LDS).
// Wl is read-only after the one-time staging: no loop barriers needed.
__global__ __launch_bounds__(256) void k_yw(float* __restrict__ yio,
                                            const float* __restrict__ Wsym,
                                            int N, int ntiles){
  __shared__ __align__(16) float Wl[64*64];
  const int t = threadIdx.x;
  #pragma unroll
  for (int q=0;q<16;q++) Wl[q*256+t] = Wsym[q*256+t];
  __syncthreads();
  const int rowg = t>>4, cg = t&15;

  for (int tile = blockIdx.x; tile < ntiles; tile += gridDim.x){
    const long r0 = (long)tile*64;
    const float* yp[4]; bool rv[4]; long rw[4];
    #pragma unroll
    for (int ri=0;ri<4;ri++){
      const long r = r0 + rowg*4 + ri;
      rv[ri] = (r < (long)N);
      const long rc = rv[ri] ? r : (long)N-1;
      yp[ri] = yio + rc*64;
      rw[ri] = rc*64;
    }
    float acc[4][4];
    #pragma unroll
    for (int ri=0;ri<4;ri++){ acc[ri][0]=0.f; acc[ri][1]=0.f; acc[ri][2]=0.f; acc[ri][3]=0.f; }
    #pragma unroll 4
    for (int ks=0;ks<16;ks++){
      const int k = 4*ks;
      const float4 b0 = *(const float4*)&Wl[(k+0)*64 + 4*cg];
      const float4 b1 = *(const float4*)&Wl[(k+1)*64 + 4*cg];
      const float4 b2 = *(const float4*)&Wl[(k+2)*64 + 4*cg];
      const float4 b3 = *(const float4*)&Wl[(k+3)*64 + 4*cg];
      #pragma unroll
      for (int ri=0;ri<4;ri++){
        const float4 a = *(const float4*)&yp[ri][k];
        acc[ri][0] += a.x*b0.x + a.y*b1.x + a.z*b2.x + a.w*b3.x;
        acc[ri][1] += a.x*b0.y + a.y*b1.y + a.z*b2.y + a.w*b3.y;
        acc[ri][2] += a.x*b0.z + a.y*b1.z + a.z*b2.z + a.w*b3.z;
        acc[ri][3] += a.x*b0.w + a.y*b1.w + a.z*b2.w + a.w*b3.w;
      }
    }
    #pragma unroll
    for (int ri=0;ri<4;ri++)
      if (rv[ri])
        *(float4*)&yio[rw[ri] + 4*cg] =
            make_float4(acc[ri][0],acc[ri][1],acc[ri][2],acc[ri][3]);
  }
}

extern "C" void kernel_launch(void* const* d_in, const int* in_sizes, int n_in,
                              void* d_out, int out_size, void* d_ws, size_t ws_size,
                              hipStream_t stream) {
  const float* x   = (const float*)d_in[0];   // [N,256]
  const float* Wfc = (const float*)d_in[1];   // [64,256]
  const float* R   = (const float*)d_in[2];   // unused: W = C^-1/2 exactly
  float* out = (float*)d_out;                 // [N,64] (holds y, then out)
  char*  ws  = (char*)d_ws;
  (void)R;

  float*          C0sum = (float*)(ws + 0);          // 16 KB
  float*          Wsym  = (float*)(ws + 16384);      // 16 KB
  unsigned short* Wh    = (unsigned short*)(ws + 32768);  // 32 KB
  unsigned short* Wlo   = (unsigned short*)(ws + 65536);  // 32 KB

  const int N = in_sizes[0] / 256;
  const int nt1 = (N + 127)/128;
  const int nt2 = (N + 63)/64;

  k_prep     <<<64,   256, 0, stream>>>(Wfc, Wh, Wlo, C0sum);
  k_pass1m   <<<1024, 256, 0, stream>>>(x, Wh, Wlo, C0sum, out, N, nt1);
  k_whiten_ns<<<1,    256, 0, stream>>>(C0sum, Wsym, 1.0f/(float)N);
  k_yw       <<<2048, 256, 0, stream>>>(out, Wsym, N, nt2);
}